// Round 8
// baseline (208.556 us; speedup 1.0000x reference)
//
#include <hip/hip_runtime.h>
#include <type_traits>

#define LMAX 24

typedef float f32x4 __attribute__((ext_vector_type(4)));
typedef float f32x2 __attribute__((ext_vector_type(2)));

// ---------- compile-time normalization table K(l,m) ----------
constexpr double csqrt_(double x) {
  double y = x > 1.0 ? x : 1.0;
  for (int i = 0; i < 300; ++i) y = 0.5 * (y + x / y);
  return y;
}
constexpr double cfact_(int n) {
  double r = 1.0;
  for (int i = 2; i <= n; ++i) r *= (double)i;
  return r;
}
constexpr double PI_ = 3.14159265358979323846;

struct KTab {
  float k[LMAX][LMAX];
  constexpr KTab() : k{} {
    for (int l = 0; l < LMAX; ++l)
      for (int m = 0; m <= l; ++m)
        k[l][m] = (float)csqrt_((2.0 * l + 1.0) * cfact_(l - m) /
                                (4.0 * PI_ * cfact_(l + m)));
  }
};
constexpr KTab KT{};
constexpr float SQRT2_ = 1.41421356237309504880f;

// ---------- compile-time loop unroller ----------
template <int N, int I = 0, typename F>
__device__ __forceinline__ void static_for(F&& f) {
  if constexpr (I < N) {
    f(std::integral_constant<int, I>{});
    static_for<N, I + 1>(f);
  }
}

// One wave (64 threads) per block; each block loops over BPB consecutive
// 64-point batches (contiguous ~864KB output region per block).
// A/B vs R7: kernel body identical; only grid shape / batching changed.
// Tests the HBM row-thrash theory: resident write streams 6250 -> 1042
// (~8 streams/channel ~ bank count) should lift the ~5.0 TB/s plateau.
//
// Staging buffer [64 points][32 j], row stride 34 dwords (8B-aligned rows):
//   emit ds_write_b64 bank: (2L+jb)%32  -> 4 dwords/bank = min phases
//   flush ds_read_b64 bank: (16t+2r+4q)%32 -> 4 dwords/bank = min phases
#define CJ 32
#define STR 34
#define BPB 6

__global__ __launch_bounds__(64) void sh_kernel(const float* __restrict__ rd,
                                                float* __restrict__ out, int n) {
  __shared__ float lds[64 * STR];

  const int lane = threadIdx.x;
  const int nbatch = (n + 63) >> 6;

  for (int bb = 0; bb < BPB; ++bb) {
    const int batch = blockIdx.x * BPB + bb;
    if (batch >= nbatch) break;

    const long long base_pt = (long long)batch * 64;
    const long long my_pt = base_pt + lane;
    const int src = my_pt < n ? (int)my_pt : 0;
    const bool full = (base_pt + 64) <= (long long)n;  // wave-uniform

    const float2 p = reinterpret_cast<const float2*>(rd)[src];
    const float D2R = 0.017453292519943295f;
    float phi = p.x * D2R;
    float theta = (p.y + 90.0f) * D2R;
    float x = cosf(theta);
    float somx2 = sqrtf((1.0f - x) * (1.0f + x));

    // cos(m*phi), sin(m*phi) via Chebyshev recurrence (register arrays)
    float cm[LMAX], sm[LMAX];
    cm[0] = 1.0f; sm[0] = 0.0f;
    float c1, s1;
    __sincosf(phi, &s1, &c1);
    cm[1] = c1; sm[1] = s1;
    float twoc = 2.0f * c1;
#pragma unroll
    for (int m = 2; m < LMAX; ++m) {
      cm[m] = twoc * cm[m - 1] - cm[m - 2];
      sm[m] = twoc * sm[m - 1] - sm[m - 2];
    }

    float cur[LMAX], prev[LMAX];
    float pmm = 1.0f;
    float b0 = 0.f;  // pending even-j value of the current pair

    float* const wptr = lds + lane * STR;  // this thread's staging row
    const float* const rbase = lds;

    // cooperative flush of chunk jc (32 j-values for all 64 points):
    // 8 passes; per pass 8 rows x 8 lanes x 16B = 8 x 128B runs.
    auto flush = [&](int jc) {
      __builtin_amdgcn_wave_barrier();
      const int r = lane >> 3;        // row sub-index within pass
      const int q = lane & 7;         // 16B column
      if (full) {
#pragma unroll
        for (int t = 0; t < 8; ++t) {
          int pp = t * 8 + r;
          int off = pp * STR + q * 4;
          f32x2 lo = *reinterpret_cast<const f32x2*>(rbase + off);
          f32x2 hi = *reinterpret_cast<const f32x2*>(rbase + off + 2);
          *reinterpret_cast<f32x4*>(out + (base_pt + pp) * (size_t)(LMAX * LMAX) +
                                    jc * CJ + q * 4) = f32x4{lo.x, lo.y, hi.x, hi.y};
        }
      } else {
#pragma unroll
        for (int t = 0; t < 8; ++t) {
          int pp = t * 8 + r;
          int off = pp * STR + q * 4;
          f32x2 lo = *reinterpret_cast<const f32x2*>(rbase + off);
          f32x2 hi = *reinterpret_cast<const f32x2*>(rbase + off + 2);
          long long pt = base_pt + pp;
          if (pt < n) {
            *reinterpret_cast<f32x4*>(out + pt * (size_t)(LMAX * LMAX) +
                                      jc * CJ + q * 4) = f32x4{lo.x, lo.y, hi.x, hi.y};
          }
        }
      }
      __builtin_amdgcn_wave_barrier();
    };

    static_for<LMAX>([&](auto LC) {
      constexpr int l = decltype(LC)::value;

      // advance recurrence state for all m < l  (gives P(l,m))
      const float ax = (float)(2 * l - 1) * x;
      static_for<l>([&](auto MC) {
        constexpr int m = decltype(MC)::value;
        constexpr float b = (float)(l + m - 1);
        constexpr float inv = 1.0f / (float)(l - m);
        float nxt = (ax * cur[m] - b * prev[m]) * inv;
        prev[m] = cur[m];
        cur[m] = nxt;
      });

      // init state for m = l:  P(l,l) = pmm,  prev = 0
      if constexpr (l > 0) {
        pmm = pmm * (-(float)(2 * l - 1)) * somx2;
      }
      cur[l] = pmm;
      prev[l] = 0.0f;

      // emit row l in j order (j = l*l + l + m, globally contiguous 0..575);
      // pair up consecutive j's -> ds_write_b64; flush every 32 values
      static_for<2 * l + 1>([&](auto KC) {
        constexpr int m = decltype(KC)::value - l;
        constexpr int am = m < 0 ? -m : m;
        constexpr int j = l * l + l + m;
        constexpr float C = (m == 0) ? KT.k[l][0] : SQRT2_ * KT.k[l][am];
        float y;
        if constexpr (m == 0) {
          y = C * cur[0];
        } else if constexpr (m > 0) {
          y = C * (cm[am] * cur[am]);
        } else {
          y = C * (sm[am] * cur[am]);
        }
        if constexpr ((j & 1) == 0) {
          b0 = y;
        } else {
          *reinterpret_cast<f32x2*>(wptr + ((j & (CJ - 1)) - 1)) = f32x2{b0, y};
        }
        if constexpr ((j & (CJ - 1)) == CJ - 1) {
          flush(j >> 5);
        }
      });
    });
  }
}

extern "C" void kernel_launch(void* const* d_in, const int* in_sizes, int n_in,
                              void* d_out, int out_size, void* d_ws, size_t ws_size,
                              hipStream_t stream) {
  (void)n_in; (void)out_size; (void)d_ws; (void)ws_size;
  const float* rd = (const float*)d_in[0];
  float* out = (float*)d_out;
  int n = in_sizes[0] / 2;
  int nbatch = (n + 63) / 64;
  int grid = (nbatch + BPB - 1) / BPB;
  sh_kernel<<<grid, 64, 0, stream>>>(rd, out, n);
}

// Round 9
// 185.992 us; speedup vs baseline: 1.1213x; 1.1213x over previous
//
#include <hip/hip_runtime.h>
#include <type_traits>

#define LMAX 24

typedef float f32x4 __attribute__((ext_vector_type(4)));
typedef float f32x2 __attribute__((ext_vector_type(2)));

// ---------- compile-time normalization table K(l,m) ----------
constexpr double csqrt_(double x) {
  double y = x > 1.0 ? x : 1.0;
  for (int i = 0; i < 300; ++i) y = 0.5 * (y + x / y);
  return y;
}
constexpr double cfact_(int n) {
  double r = 1.0;
  for (int i = 2; i <= n; ++i) r *= (double)i;
  return r;
}
constexpr double PI_ = 3.14159265358979323846;

struct KTab {
  float k[LMAX][LMAX];
  constexpr KTab() : k{} {
    for (int l = 0; l < LMAX; ++l)
      for (int m = 0; m <= l; ++m)
        k[l][m] = (float)csqrt_((2.0 * l + 1.0) * cfact_(l - m) /
                                (4.0 * PI_ * cfact_(l + m)));
  }
};
constexpr KTab KT{};
constexpr float SQRT2_ = 1.41421356237309504880f;

// ---------- compile-time loop unroller ----------
template <int N, int I = 0, typename F>
__device__ __forceinline__ void static_for(F&& f) {
  if constexpr (I < N) {
    f(std::integral_constant<int, I>{});
    static_for<N, I + 1>(f);
  }
}

// 256-thread blocks, 4 waves; wave w handles batch 4*blockIdx + w, so each
// block writes a CONTIGUOUS 576KB output region. A/B vs R7 (same DS config,
// same 16 waves/CU occupancy, 1-wave-sized work units): concurrently-active
// HBM regions drop ~4096 -> ~1024. Tests the bank-row-thrash theory.
//
// Staging [64 points][32 j], row stride 34 dwords (8B-aligned rows):
//   emit ds_write_b64 bank: (2L+jb)%32     -> 4 dwords/bank = min phases
//   flush ds_read_b64 bank: (16t+2r+4q)%32 -> 4 dwords/bank = min phases
// Waves use private LDS quadrants; only wave_barrier (no s_barrier).
#define CJ 32
#define STR 34

__global__ __launch_bounds__(256) void sh_kernel(const float* __restrict__ rd,
                                                 float* __restrict__ out, int n) {
  __shared__ float lds[4 * 64 * STR];

  const int tid = threadIdx.x;
  const int wave = tid >> 6;
  const int lane = tid & 63;
  const int nbatch = (n + 63) >> 6;
  const int batch = blockIdx.x * 4 + wave;
  if (batch >= nbatch) return;  // wave-uniform exit, no block barriers used

  const long long base_pt = (long long)batch * 64;
  const long long my_pt = base_pt + lane;
  const int src = my_pt < n ? (int)my_pt : 0;
  const bool full = (base_pt + 64) <= (long long)n;  // wave-uniform

  const float2 p = reinterpret_cast<const float2*>(rd)[src];
  const float D2R = 0.017453292519943295f;
  float phi = p.x * D2R;
  float theta = (p.y + 90.0f) * D2R;
  float x = cosf(theta);
  float somx2 = sqrtf((1.0f - x) * (1.0f + x));

  // cos(m*phi), sin(m*phi) via Chebyshev recurrence (register arrays)
  float cm[LMAX], sm[LMAX];
  cm[0] = 1.0f; sm[0] = 0.0f;
  float c1, s1;
  __sincosf(phi, &s1, &c1);
  cm[1] = c1; sm[1] = s1;
  float twoc = 2.0f * c1;
#pragma unroll
  for (int m = 2; m < LMAX; ++m) {
    cm[m] = twoc * cm[m - 1] - cm[m - 2];
    sm[m] = twoc * sm[m - 1] - sm[m - 2];
  }

  float cur[LMAX], prev[LMAX];
  float pmm = 1.0f;
  float b0 = 0.f;  // pending even-j value of the current pair

  float* const wptr = lds + wave * (64 * STR) + lane * STR;  // thread's row
  const float* const rbase = lds + wave * (64 * STR);         // wave's buffer

  // cooperative flush of chunk jc (32 j-values for the wave's 64 points):
  // 8 passes; per pass 8 rows x 8 lanes x 16B = 8 x 128B runs.
  auto flush = [&](int jc) {
    __builtin_amdgcn_wave_barrier();
    const int r = lane >> 3;        // row sub-index within pass
    const int q = lane & 7;         // 16B column
    if (full) {
#pragma unroll
      for (int t = 0; t < 8; ++t) {
        int pp = t * 8 + r;
        int off = pp * STR + q * 4;
        f32x2 lo = *reinterpret_cast<const f32x2*>(rbase + off);
        f32x2 hi = *reinterpret_cast<const f32x2*>(rbase + off + 2);
        *reinterpret_cast<f32x4*>(out + (base_pt + pp) * (size_t)(LMAX * LMAX) +
                                  jc * CJ + q * 4) = f32x4{lo.x, lo.y, hi.x, hi.y};
      }
    } else {
#pragma unroll
      for (int t = 0; t < 8; ++t) {
        int pp = t * 8 + r;
        int off = pp * STR + q * 4;
        f32x2 lo = *reinterpret_cast<const f32x2*>(rbase + off);
        f32x2 hi = *reinterpret_cast<const f32x2*>(rbase + off + 2);
        long long pt = base_pt + pp;
        if (pt < n) {
          *reinterpret_cast<f32x4*>(out + pt * (size_t)(LMAX * LMAX) +
                                    jc * CJ + q * 4) = f32x4{lo.x, lo.y, hi.x, hi.y};
        }
      }
    }
    __builtin_amdgcn_wave_barrier();
  };

  static_for<LMAX>([&](auto LC) {
    constexpr int l = decltype(LC)::value;

    // advance recurrence state for all m < l  (gives P(l,m))
    const float ax = (float)(2 * l - 1) * x;
    static_for<l>([&](auto MC) {
      constexpr int m = decltype(MC)::value;
      constexpr float b = (float)(l + m - 1);
      constexpr float inv = 1.0f / (float)(l - m);
      float nxt = (ax * cur[m] - b * prev[m]) * inv;
      prev[m] = cur[m];
      cur[m] = nxt;
    });

    // init state for m = l:  P(l,l) = pmm,  prev = 0
    if constexpr (l > 0) {
      pmm = pmm * (-(float)(2 * l - 1)) * somx2;
    }
    cur[l] = pmm;
    prev[l] = 0.0f;

    // emit row l in j order (j = l*l + l + m, globally contiguous 0..575);
    // pair up consecutive j's -> ds_write_b64; flush every 32 values
    static_for<2 * l + 1>([&](auto KC) {
      constexpr int m = decltype(KC)::value - l;
      constexpr int am = m < 0 ? -m : m;
      constexpr int j = l * l + l + m;
      constexpr float C = (m == 0) ? KT.k[l][0] : SQRT2_ * KT.k[l][am];
      float y;
      if constexpr (m == 0) {
        y = C * cur[0];
      } else if constexpr (m > 0) {
        y = C * (cm[am] * cur[am]);
      } else {
        y = C * (sm[am] * cur[am]);
      }
      if constexpr ((j & 1) == 0) {
        b0 = y;
      } else {
        *reinterpret_cast<f32x2*>(wptr + ((j & (CJ - 1)) - 1)) = f32x2{b0, y};
      }
      if constexpr ((j & (CJ - 1)) == CJ - 1) {
        flush(j >> 5);
      }
    });
  });
}

extern "C" void kernel_launch(void* const* d_in, const int* in_sizes, int n_in,
                              void* d_out, int out_size, void* d_ws, size_t ws_size,
                              hipStream_t stream) {
  (void)n_in; (void)out_size; (void)d_ws; (void)ws_size;
  const float* rd = (const float*)d_in[0];
  float* out = (float*)d_out;
  int n = in_sizes[0] / 2;
  int nbatch = (n + 63) / 64;
  int grid = (nbatch + 3) / 4;  // 4 consecutive batches per 4-wave block
  sh_kernel<<<grid, 256, 0, stream>>>(rd, out, n);
}